// Round 4
// baseline (315.786 us; speedup 1.0000x reference)
//
#include <hip/hip_runtime.h>
#include <math.h>

#define NN 50000
#define NE 600000
#define NG 512
#define NCHUNK 4
#define CHUNK 12500            // 12500 rows * 256 B = 3.2 MB < 4 MB per-XCD L2
#define NBUCK (NN * NCHUNK)    // 200000 buckets keyed (node, src_chunk)
#define NSCAN_BLK 782          // ceil(NBUCK/256)

typedef unsigned int u32;
typedef unsigned short u16;

typedef __attribute__((ext_vector_type(8))) short bf16x8;
typedef __attribute__((ext_vector_type(4))) float f32x4;
typedef __attribute__((ext_vector_type(4))) unsigned int u32x4;

__device__ __forceinline__ float bf2f(u16 u) {
  return __uint_as_float(((u32)u) << 16);
}
__device__ __forceinline__ u16 f2bf(float f) {
  u32 u = __float_as_uint(f);
  u32 lsb = (u >> 16) & 1u;
  u += 0x7fffu + lsb;          // RNE
  return (u16)(u >> 16);
}

// ================= CSR build over (dst, src_chunk) buckets ========
__global__ __launch_bounds__(256)
void deg_count_k(const int* __restrict__ ei, int* __restrict__ deg) {
  int e = blockIdx.x * 256 + threadIdx.x;
  if (e >= NE) return;
  u32 src = (u32)ei[e];
  int bucket = ei[NE + e] * NCHUNK + (int)(src / CHUNK);
  atomicAdd(&deg[bucket], 1);
}

// phase 1: per-block (256-wide) sums of deg -> bsum[782]
__global__ __launch_bounds__(256)
void scan1_k(const int* __restrict__ deg, int* __restrict__ bsum) {
  __shared__ int s[256];
  int idx = blockIdx.x * 256 + threadIdx.x;
  int v = (idx < NBUCK) ? deg[idx] : 0;
  s[threadIdx.x] = v;
  __syncthreads();
  for (int off = 128; off > 0; off >>= 1) {
    if (threadIdx.x < off) s[threadIdx.x] += s[threadIdx.x + off];
    __syncthreads();
  }
  if (threadIdx.x == 0) bsum[blockIdx.x] = s[0];
}

// phase 2: single 1024-thread block scans the 782 block sums -> bofs (exclusive)
__global__ __launch_bounds__(1024)
void scan2_k(const int* __restrict__ bsum, int* __restrict__ bofs, int* __restrict__ row_ptr) {
  __shared__ int s[1024];
  int t = threadIdx.x;
  int v = (t < NSCAN_BLK) ? bsum[t] : 0;
  s[t] = v;
  __syncthreads();
  for (int off = 1; off < 1024; off <<= 1) {
    int add = (t >= off) ? s[t - off] : 0;
    __syncthreads();
    s[t] += add;
    __syncthreads();
  }
  if (t < NSCAN_BLK) bofs[t] = s[t] - v;     // exclusive
  if (t == 0) row_ptr[NBUCK] = NE;
}

// phase 3: per-block exclusive scan + block offset -> row_ptr, cursor
// cursor aliases deg's memory (deg is dead after this kernel reads it).
__global__ __launch_bounds__(256)
void scan3_k(const int* __restrict__ deg, const int* __restrict__ bofs,
             int* __restrict__ row_ptr, int* __restrict__ cursor) {
  __shared__ int s[256];
  int idx = blockIdx.x * 256 + threadIdx.x;
  int t = threadIdx.x;
  int v = (idx < NBUCK) ? deg[idx] : 0;
  s[t] = v;
  __syncthreads();
  for (int off = 1; off < 256; off <<= 1) {
    int add = (t >= off) ? s[t - off] : 0;
    __syncthreads();
    s[t] += add;
    __syncthreads();
  }
  if (idx < NBUCK) {
    int p = bofs[blockIdx.x] + s[t] - v;
    row_ptr[idx] = p;
    cursor[idx] = p;
  }
}

__global__ __launch_bounds__(256)
void fill_k(const int* __restrict__ ei, int* __restrict__ cursor, int* __restrict__ perm) {
  int e = blockIdx.x * 256 + threadIdx.x;
  if (e >= NE) return;
  u32 src = (u32)ei[e];
  int bucket = ei[NE + e] * NCHUNK + (int)(src / CHUNK);
  int pos = atomicAdd(&cursor[bucket], 1);
  perm[pos] = (int)src;
}

// ================= cast x (f32) -> xb (bf16) =================
__global__ __launch_bounds__(256)
void cast_k(const float* __restrict__ x, u32* __restrict__ xb) {
  int tid = blockIdx.x * 256 + threadIdx.x;       // 12500*256 = 3,200,000 exactly
  float2 v = ((const float2*)x)[tid];
  xb[tid] = (u32)f2bf(v.x) | ((u32)f2bf(v.y) << 16);
}

// ===== weight cast+transpose, PRE-SWIZZLED for LDS bank-conflict-free ds_read_b128 =====
// logical WbT[n][k] = bf16( k<128 ? Wl[k][n] : Wr[k-128][n] ), stored with the 16B chunk
// index XOR'd by (n&7):  k = c*8+e  ->  idx = n*256 + ((c ^ (n&7))<<3) + e
__global__ __launch_bounds__(256)
void castW_k(const float* __restrict__ Wl, const float* __restrict__ Wr,
             u16* __restrict__ WbT, int ncols) {   // ncols = 128 or 64
  int t = blockIdx.x * 256 + threadIdx.x;          // ncols*256 threads
  int n = t >> 8;
  int k = t & 255;
  if (n >= ncols) return;
  float v = (k < 128) ? Wl[k * ncols + n] : Wr[(k - 128) * ncols + n];
  int c = k >> 3, e = k & 7;
  WbT[n * 256 + (((c ^ (n & 7)) << 3) | e)] = f2bf(v);
}

// ===== gather-mean v3: src-chunked for L2 residency =====
// 4 nodes per wave (grp = lane>>4), lane16 owns 16 B of the row (dwordx4).
// Outer loop over 4 src-chunks: all waves process chunk c at roughly the same
// time (launched together, equal expected work) -> GPU-wide working set is one
// 3.2 MB slice of xb -> L2-resident. Accumulate across chunks, divide by total.
__global__ __launch_bounds__(256)
void gather4_k(const u16* __restrict__ xb, const int* __restrict__ row_ptr,
               const int* __restrict__ perm, u16* __restrict__ aggb) {
  int wave = threadIdx.x >> 6;
  int lane = threadIdx.x & 63;
  int grp  = lane >> 4;
  int l16  = lane & 15;
  int n = (blockIdx.x * 4 + wave) * 4 + grp;     // 3125*4*4 = 50000
  float acc[8];
#pragma unroll
  for (int i = 0; i < 8; i++) acc[i] = 0.f;
  const u32x4* xv = (const u32x4*)xb;            // row = 16 chunks of 16 B
  int tot = row_ptr[n * NCHUNK + NCHUNK] - row_ptr[n * NCHUNK];
  for (int c = 0; c < NCHUNK; c++) {
    int b0 = row_ptr[n * NCHUNK + c];
    int cnt = row_ptr[n * NCHUNK + c + 1] - b0;
    int beg_s = min(b0, NE - 1);                 // safe base for clamped reads
    int last = max(cnt - 1, 0);
    int m = max(cnt, __shfl_xor(cnt, 16));
    int jmax = max(m, __shfl_xor(m, 32));        // wave-uniform loop bound
    for (int base = 0; base < jmax; base += 8) {
      int idx[8];
#pragma unroll
      for (int j = 0; j < 8; j++) idx[j] = perm[beg_s + min(base + j, last)];
      u32x4 v[8];
#pragma unroll
      for (int j = 0; j < 8; j++) v[j] = xv[(size_t)idx[j] * 16 + l16];
#pragma unroll
      for (int j = 0; j < 8; j++) {
        bool live = (base + j) < cnt;
#pragma unroll
        for (int w = 0; w < 4; w++) {
          u32 u = v[j][w];
          acc[2 * w]     += live ? __uint_as_float(u << 16) : 0.f;
          acc[2 * w + 1] += live ? __uint_as_float(u & 0xffff0000u) : 0.f;
        }
      }
    }
  }
  float inv = 1.0f / fmaxf((float)tot, 1.0f);
  u32x4 o;
#pragma unroll
  for (int w = 0; w < 4; w++)
    o[w] = (u32)f2bf(acc[2 * w] * inv) | ((u32)f2bf(acc[2 * w + 1] * inv) << 16);
  ((u32x4*)aggb)[(size_t)n * 16 + l16] = o;
}

// ===== MFMA SAGE layer v2: block = 64 rows x NCOL cols, W staged in LDS once =====
// 4 waves; wave = 16 rows x NCOL cols (NCOL/16 col-tiles, 8 K-steps, K=256).
// A loaded direct from global (8x bf16x8 per lane, prefetched); B from swizzled LDS.
// SOFTMAX variant (NCOL=64): fused wave-parallel log-softmax epilogue, no LDS roundtrip.
template<int NCOL, bool WRITE_PRE, bool SOFTMAX>
__global__ __launch_bounds__(256)
void sage_mfma_v2_k(const u16* __restrict__ aggb, const u16* __restrict__ xbin,
                    const u16* __restrict__ WbT, const float* __restrict__ bl,
                    u16* __restrict__ xb_out, float* __restrict__ out_pre,
                    float* __restrict__ out_f) {
  __shared__ u16 wsh[NCOL * 256];        // 64 KB (NCOL=128) / 32 KB (NCOL=64)
  int tid = threadIdx.x;

  // ---- stage pre-swizzled W into LDS (linear 16B-chunk copy, conflict-free) ----
  {
    const u32x4* g = (const u32x4*)WbT;
    u32x4* l = (u32x4*)wsh;
#pragma unroll
    for (int i = 0; i < NCOL / 8; i++)   // NCOL*512B / (256 thr * 16B)
      l[tid + i * 256] = g[tid + i * 256];
  }
  __syncthreads();

  int wave = tid >> 6;
  int lane = tid & 63;
  int quad = lane >> 4;
  int m16  = lane & 15;
  int r0 = blockIdx.x * 64 + wave * 16;

  // ---- prefetch all 8 A fragments (rows clamped; OOB rows never stored) ----
  int rowA = min(r0 + m16, NN - 1);
  const u16* pa = aggb + (size_t)rowA * 128 + quad * 8;
  const u16* px = xbin + (size_t)rowA * 128 + quad * 8;
  bf16x8 a[8];
#pragma unroll
  for (int j = 0; j < 4; j++) a[j]     = *(const bf16x8*)(pa + j * 32);
#pragma unroll
  for (int j = 0; j < 4; j++) a[4 + j] = *(const bf16x8*)(px + j * 32);

  constexpr int NT = NCOL / 16;
  f32x4 acc[NT];
#pragma unroll
  for (int nt = 0; nt < NT; nt++) acc[nt] = (f32x4){0.f, 0.f, 0.f, 0.f};

  int swz = m16 & 7;
#pragma unroll
  for (int ks = 0; ks < 8; ks++) {
#pragma unroll
    for (int nt = 0; nt < NT; nt++) {
      const u16* bp = wsh + (nt * 16 + m16) * 256 + (((quad + ks * 4) ^ swz) << 3);
      bf16x8 b = *(const bf16x8*)bp;
      acc[nt] = __builtin_amdgcn_mfma_f32_16x16x32_bf16(a[ks], b, acc[nt], 0, 0, 0);
    }
  }

  float bv[NT];
#pragma unroll
  for (int nt = 0; nt < NT; nt++) bv[nt] = bl[nt * 16 + m16];

  int rbase = r0 + quad * 4;
  if (!SOFTMAX) {
#pragma unroll
    for (int r = 0; r < 4; r++) {
      int row = rbase + r;
      if (row < NN) {
#pragma unroll
        for (int nt = 0; nt < NT; nt++) {
          int col = nt * 16 + m16;
          float v = acc[nt][r] + bv[nt];
          if (WRITE_PRE) out_pre[(size_t)row * NCOL + col] = v;
          xb_out[(size_t)row * NCOL + col] = f2bf(fmaxf(v, 0.f));
        }
      }
    }
  } else {
    // NCOL==64: bias + in-register log-softmax across 4 regs x 16 lanes (m16 group)
#pragma unroll
    for (int r = 0; r < 4; r++) {
      float v0 = acc[0][r] + bv[0];
      float v1 = acc[1][r] + bv[1];
      float v2 = acc[2][r] + bv[2];
      float v3 = acc[3][r] + bv[3];
      float m = fmaxf(fmaxf(v0, v1), fmaxf(v2, v3));
#pragma unroll
      for (int mk = 1; mk <= 8; mk <<= 1) m = fmaxf(m, __shfl_xor(m, mk));
      float s = __expf(v0 - m) + __expf(v1 - m) + __expf(v2 - m) + __expf(v3 - m);
#pragma unroll
      for (int mk = 1; mk <= 8; mk <<= 1) s += __shfl_xor(s, mk);
      float ls = m + __logf(s);
      int row = rbase + r;
      if (row < NN) {
        float* orow = out_f + (size_t)row * 64;
        orow[m16]      = v0 - ls;
        orow[16 + m16] = v1 - ls;
        orow[32 + m16] = v2 - ls;
        orow[48 + m16] = v3 - ls;
      }
    }
  }
}

// ======= graph pooling v2: 256 thr/block, odd/even node split + LDS combine =======
__global__ __launch_bounds__(256)
void pool_seg_k(const u16* __restrict__ xb, const int* __restrict__ cluster,
                float* __restrict__ g) {
  __shared__ float sh[256];
  int gid = blockIdx.x;          // 512
  int t = threadIdx.x;
  int ch = t & 127;
  int half = t >> 7;
  int lo = 0, hi = NN;
  while (lo < hi) { int mid = (lo + hi) >> 1; if (cluster[mid] < gid) lo = mid + 1; else hi = mid; }
  int beg = lo;
  hi = NN;
  while (lo < hi) { int mid = (lo + hi) >> 1; if (cluster[mid] < gid + 1) lo = mid + 1; else hi = mid; }
  int end = lo;
  float s0 = 0.f, s1 = 0.f;
  int n = beg + half;            // this half handles nodes beg+half, +2, +4, ...
  for (; n + 2 < end; n += 4) {
    s0 += bf2f(xb[(size_t)n * 128 + ch]);
    s1 += bf2f(xb[(size_t)(n + 2) * 128 + ch]);
  }
  if (n < end) s0 += bf2f(xb[(size_t)n * 128 + ch]);
  sh[t] = s0 + s1;
  __syncthreads();
  if (t < 128) {
    float s = sh[t] + sh[t + 128];
    g[gid * 128 + t] = s / fmaxf((float)(end - beg), 1.0f);
  }
}

extern "C" void kernel_launch(void* const* d_in, const int* in_sizes, int n_in,
                              void* d_out, int out_size, void* d_ws, size_t ws_size,
                              hipStream_t stream) {
  const float* x   = (const float*)d_in[0];
  const int*   ei  = (const int*)d_in[1];
  const int*   cl  = (const int*)d_in[2];
  const float* Wl0 = (const float*)d_in[3];
  const float* bl0 = (const float*)d_in[4];
  const float* Wr0 = (const float*)d_in[5];
  const float* Wl1 = (const float*)d_in[6];
  const float* bl1 = (const float*)d_in[7];
  const float* Wr1 = (const float*)d_in[8];
  const float* Wl2 = (const float*)d_in[9];
  const float* bl2 = (const float*)d_in[10];
  const float* Wr2 = (const float*)d_in[11];
  float* out = (float*)d_out;

  char* ws = (char*)d_ws;
  u16*   xb0     = (u16*)  (ws);                  // 12,800,000 B (bf16 of x)
  u16*   xb1     = (u16*)  (ws + 12800000);       // 12,800,000 B (relu layer0)
  u16*   xb2     = (u16*)  (ws + 25600000);       // 12,800,000 B (relu layer1)
  u16*   aggb    = (u16*)  (ws + 38400000);       // 12,800,000 B
  u16*   WbT0    = (u16*)  (ws + 51200000);       //     65,536 B (pre-swizzled)
  u16*   WbT1    = (u16*)  (ws + 51265536);       //     65,536 B (pre-swizzled)
  u16*   WbT2    = (u16*)  (ws + 51331072);       //     32,768 B (pre-swizzled)
  int*   deg     = (int*)  (ws + 51363840);       //    800,000 B (aliased: cursor)
  int*   row_ptr = (int*)  (ws + 52163840);       //    800,068 B (+pad)
  int*   perm    = (int*)  (ws + 52963968);       //  2,400,000 B
  int*   bsum    = (int*)  (ws + 55363968);       //      3,200 B
  int*   bofs    = (int*)  (ws + 55367168);       //      3,200 B
  // total ~55.4 MB
  int*   cursor  = deg;            // deg is dead after scan3 reads it

  float* out_lsm = out;            // [50000,64]
  float* out_pre = out + 3200000;  // [50000,128]
  float* out_g   = out + 9600000;  // [512,128]

  // ---- CSR build over (dst, src_chunk) buckets ----
  hipMemsetAsync(deg, 0, NBUCK * 4, stream);
  deg_count_k<<<2344, 256, 0, stream>>>(ei, deg);
  scan1_k<<<NSCAN_BLK, 256, 0, stream>>>(deg, bsum);
  scan2_k<<<1, 1024, 0, stream>>>(bsum, bofs, row_ptr);
  scan3_k<<<NSCAN_BLK, 256, 0, stream>>>(deg, bofs, row_ptr, cursor);
  fill_k<<<2344, 256, 0, stream>>>(ei, cursor, perm);

  // ---- casts (x and weights) ----
  cast_k<<<12500, 256, 0, stream>>>(x, (u32*)xb0);
  castW_k<<<128, 256, 0, stream>>>(Wl0, Wr0, WbT0, 128);
  castW_k<<<128, 256, 0, stream>>>(Wl1, Wr1, WbT1, 128);
  castW_k<<<64, 256, 0, stream>>>(Wl2, Wr2, WbT2, 64);

  // ---- layer 0 ----
  gather4_k<<<3125, 256, 0, stream>>>(xb0, row_ptr, perm, aggb);
  sage_mfma_v2_k<128, false, false><<<782, 256, 0, stream>>>(aggb, xb0, WbT0, bl0, xb1, nullptr, nullptr);

  // ---- layer 1 (pre-relu f32 straight to d_out) ----
  gather4_k<<<3125, 256, 0, stream>>>(xb1, row_ptr, perm, aggb);
  sage_mfma_v2_k<128, true, false><<<782, 256, 0, stream>>>(aggb, xb1, WbT1, bl1, xb2, out_pre, nullptr);

  // ---- graph pooling of relu(layer1) ----
  pool_seg_k<<<NG, 256, 0, stream>>>(xb2, cl, out_g);

  // ---- final layer + fused log_softmax ----
  gather4_k<<<3125, 256, 0, stream>>>(xb2, row_ptr, perm, aggb);
  sage_mfma_v2_k<64, false, true><<<782, 256, 0, stream>>>(aggb, xb2, WbT2, bl2, nullptr, nullptr, out_lsm);
}

// Round 5
// 301.567 us; speedup vs baseline: 1.0472x; 1.0472x over previous
//
#include <hip/hip_runtime.h>
#include <math.h>

#define NN 50000
#define NE 600000
#define NG 512

typedef unsigned int u32;
typedef unsigned short u16;

typedef __attribute__((ext_vector_type(8))) short bf16x8;
typedef __attribute__((ext_vector_type(4))) float f32x4;
typedef __attribute__((ext_vector_type(4))) unsigned int u32x4;

__device__ __forceinline__ float bf2f(u16 u) {
  return __uint_as_float(((u32)u) << 16);
}
__device__ __forceinline__ u16 f2bf(float f) {
  u32 u = __float_as_uint(f);
  u32 lsb = (u >> 16) & 1u;
  u += 0x7fffu + lsb;          // RNE
  return (u16)(u >> 16);
}

// ================= CSR build (once per launch) ========
__global__ __launch_bounds__(256)
void deg_count_k(const int* __restrict__ ei, int* __restrict__ deg) {
  int e = blockIdx.x * 256 + threadIdx.x;
  if (e >= NE) return;
  atomicAdd(&deg[ei[NE + e]], 1);
}

// phase 1: per-block (256-wide) sums of deg -> bsum[196]
__global__ __launch_bounds__(256)
void scan1_k(const int* __restrict__ deg, int* __restrict__ bsum) {
  __shared__ int s[256];
  int idx = blockIdx.x * 256 + threadIdx.x;
  int v = (idx < NN) ? deg[idx] : 0;
  s[threadIdx.x] = v;
  __syncthreads();
  for (int off = 128; off > 0; off >>= 1) {
    if (threadIdx.x < off) s[threadIdx.x] += s[threadIdx.x + off];
    __syncthreads();
  }
  if (threadIdx.x == 0) bsum[blockIdx.x] = s[0];
}

// phase 2: single block scans the 196 block sums -> bofs (exclusive); row_ptr[NN] = NE
__global__ __launch_bounds__(256)
void scan2_k(const int* __restrict__ bsum, int* __restrict__ bofs, int* __restrict__ row_ptr) {
  __shared__ int s[256];
  int t = threadIdx.x;
  int v = (t < 196) ? bsum[t] : 0;
  s[t] = v;
  __syncthreads();
  for (int off = 1; off < 256; off <<= 1) {
    int add = (t >= off) ? s[t - off] : 0;
    __syncthreads();
    s[t] += add;
    __syncthreads();
  }
  if (t < 196) bofs[t] = s[t] - v;     // exclusive
  if (t == 0) row_ptr[NN] = NE;
}

// phase 3: per-block exclusive scan + block offset -> row_ptr, cursor
__global__ __launch_bounds__(256)
void scan3_k(const int* __restrict__ deg, const int* __restrict__ bofs,
             int* __restrict__ row_ptr, int* __restrict__ cursor) {
  __shared__ int s[256];
  int idx = blockIdx.x * 256 + threadIdx.x;
  int t = threadIdx.x;
  int v = (idx < NN) ? deg[idx] : 0;
  s[t] = v;
  __syncthreads();
  for (int off = 1; off < 256; off <<= 1) {
    int add = (t >= off) ? s[t - off] : 0;
    __syncthreads();
    s[t] += add;
    __syncthreads();
  }
  if (idx < NN) {
    int p = bofs[blockIdx.x] + s[t] - v;
    row_ptr[idx] = p;
    cursor[idx] = p;
  }
}

__global__ __launch_bounds__(256)
void fill_k(const int* __restrict__ ei, int* __restrict__ cursor, int* __restrict__ perm) {
  int e = blockIdx.x * 256 + threadIdx.x;
  if (e >= NE) return;
  int pos = atomicAdd(&cursor[ei[NE + e]], 1);
  perm[pos] = ei[e];
}

// ================= cast x (f32) -> xb (bf16) =================
__global__ __launch_bounds__(256)
void cast_k(const float* __restrict__ x, u32* __restrict__ xb) {
  int tid = blockIdx.x * 256 + threadIdx.x;       // 12500*256 = 3,200,000 exactly
  float2 v = ((const float2*)x)[tid];
  xb[tid] = (u32)f2bf(v.x) | ((u32)f2bf(v.y) << 16);
}

// ===== weight cast+transpose K=256 ([Wl;Wr]), PRE-SWIZZLED for LDS b128 reads =====
// logical WbT[n][k], stored with 16B-chunk index XOR'd by (n&7).
__global__ __launch_bounds__(256)
void castW_k(const float* __restrict__ Wl, const float* __restrict__ Wr,
             u16* __restrict__ WbT, int ncols) {   // ncols = 128
  int t = blockIdx.x * 256 + threadIdx.x;          // ncols*256 threads
  int n = t >> 8;
  int k = t & 255;
  if (n >= ncols) return;
  float v = (k < 128) ? Wl[k * ncols + n] : Wr[(k - 128) * ncols + n];
  int c = k >> 3, e = k & 7;
  WbT[n * 256 + (((c ^ (n & 7)) << 3) | e)] = f2bf(v);
}

// ===== single-weight cast+transpose K=128 (64 out cols), pre-swizzled =====
__global__ __launch_bounds__(256)
void castW64_k(const float* __restrict__ W, u16* __restrict__ WT) {
  int t = blockIdx.x * 256 + threadIdx.x;          // 64*128 = 8192 threads (32 blocks)
  int n = t >> 7;          // 0..63
  int k = t & 127;
  float v = W[k * 64 + n];
  int c = k >> 3, e = k & 7;
  WT[n * 128 + (((c ^ (n & 7)) << 3) | e)] = f2bf(v);
}

// ===== gather-mean v4: 1 node per wave, exact per-node bound =====
// CH channels (128 or 64). Each dwordx4 instruction loads GR=64/(CH/8) neighbor
// rows (CH/8 lanes per row, 16 B each). Exact loop bound (base<cnt) so tail
// waste is <= 2*GR-1 clamped dup-loads (L1-absorbed). Cross-group shfl reduce.
template<int CH>
__global__ __launch_bounds__(256)
void gather_w_k(const u16* __restrict__ xb, const int* __restrict__ row_ptr,
                const int* __restrict__ perm, u16* __restrict__ aggb) {
  constexpr int CK = CH / 8;          // 16B chunks per row (16 or 8)
  constexpr int GR = 64 / CK;         // neighbor rows per load instr (4 or 8)
  int wave = threadIdx.x >> 6;
  int lane = threadIdx.x & 63;
  int grp  = lane / CK;               // neighbor slot within instruction
  int li   = lane & (CK - 1);         // 16B chunk within row
  int n = blockIdx.x * 4 + wave;      // 12500 * 4 = 50000
  int beg = row_ptr[n];
  int cnt = row_ptr[n + 1] - beg;
  int beg_s = min(beg, NE - 1);       // safe base for clamped reads
  int last = max(cnt - 1, 0);
  float acc[8];
#pragma unroll
  for (int i = 0; i < 8; i++) acc[i] = 0.f;
  const u32x4* xv = (const u32x4*)xb;
  for (int base = 0; base < cnt; base += 2 * GR) {
    int i0 = perm[beg_s + min(base + grp, last)];
    int i1 = perm[beg_s + min(base + GR + grp, last)];
    u32x4 v0 = xv[(size_t)i0 * CK + li];
    u32x4 v1 = xv[(size_t)i1 * CK + li];
    bool a0 = (base + grp) < cnt;
    bool a1 = (base + GR + grp) < cnt;
#pragma unroll
    for (int w = 0; w < 4; w++) {
      acc[2 * w]     += a0 ? __uint_as_float(v0[w] << 16) : 0.f;
      acc[2 * w + 1] += a0 ? __uint_as_float(v0[w] & 0xffff0000u) : 0.f;
      acc[2 * w]     += a1 ? __uint_as_float(v1[w] << 16) : 0.f;
      acc[2 * w + 1] += a1 ? __uint_as_float(v1[w] & 0xffff0000u) : 0.f;
    }
  }
  // reduce across neighbor groups: lanes at stride CK hold same channels
#pragma unroll
  for (int off = CK; off < 64; off <<= 1) {
#pragma unroll
    for (int i = 0; i < 8; i++) acc[i] += __shfl_xor(acc[i], off);
  }
  float inv = 1.0f / fmaxf((float)cnt, 1.0f);
  if (lane < CK) {
    u32x4 o;
#pragma unroll
    for (int w = 0; w < 4; w++)
      o[w] = (u32)f2bf(acc[2 * w] * inv) | ((u32)f2bf(acc[2 * w + 1] * inv) << 16);
    ((u32x4*)aggb)[(size_t)n * CK + li] = o;
  }
}

// ===== MFMA SAGE layer (Cout=128): block = 64 rows x 128 cols, W (K=256) in LDS =====
template<bool WRITE_PRE>
__global__ __launch_bounds__(256)
void sage_mfma_v2_k(const u16* __restrict__ aggb, const u16* __restrict__ xbin,
                    const u16* __restrict__ WbT, const float* __restrict__ bl,
                    u16* __restrict__ xb_out, float* __restrict__ out_pre) {
  __shared__ u16 wsh[128 * 256];        // 64 KB
  int tid = threadIdx.x;
  {
    const u32x4* g = (const u32x4*)WbT;
    u32x4* l = (u32x4*)wsh;
#pragma unroll
    for (int i = 0; i < 16; i++)
      l[tid + i * 256] = g[tid + i * 256];
  }
  __syncthreads();

  int wave = tid >> 6;
  int lane = tid & 63;
  int quad = lane >> 4;
  int m16  = lane & 15;
  int r0 = blockIdx.x * 64 + wave * 16;

  int rowA = min(r0 + m16, NN - 1);
  const u16* pa = aggb + (size_t)rowA * 128 + quad * 8;
  const u16* px = xbin + (size_t)rowA * 128 + quad * 8;
  bf16x8 a[8];
#pragma unroll
  for (int j = 0; j < 4; j++) a[j]     = *(const bf16x8*)(pa + j * 32);
#pragma unroll
  for (int j = 0; j < 4; j++) a[4 + j] = *(const bf16x8*)(px + j * 32);

  f32x4 acc[8];
#pragma unroll
  for (int nt = 0; nt < 8; nt++) acc[nt] = (f32x4){0.f, 0.f, 0.f, 0.f};

  int swz = m16 & 7;
#pragma unroll
  for (int ks = 0; ks < 8; ks++) {
#pragma unroll
    for (int nt = 0; nt < 8; nt++) {
      const u16* bp = wsh + (nt * 16 + m16) * 256 + (((quad + ks * 4) ^ swz) << 3);
      bf16x8 b = *(const bf16x8*)bp;
      acc[nt] = __builtin_amdgcn_mfma_f32_16x16x32_bf16(a[ks], b, acc[nt], 0, 0, 0);
    }
  }

  float bv[8];
#pragma unroll
  for (int nt = 0; nt < 8; nt++) bv[nt] = bl[nt * 16 + m16];

  int rbase = r0 + quad * 4;
#pragma unroll
  for (int r = 0; r < 4; r++) {
    int row = rbase + r;
    if (row < NN) {
#pragma unroll
      for (int nt = 0; nt < 8; nt++) {
        int col = nt * 16 + m16;
        float v = acc[nt][r] + bv[nt];
        if (WRITE_PRE) out_pre[(size_t)row * 128 + col] = v;
        xb_out[(size_t)row * 128 + col] = f2bf(fmaxf(v, 0.f));
      }
    }
  }
}

// ===== pre-GEMM for final layer: y2 = xb2 @ Wl2 (K=128 -> 64 cols, bf16 out) =====
__global__ __launch_bounds__(256)
void gemm64_k(const u16* __restrict__ xbin, const u16* __restrict__ WT,
              u16* __restrict__ yb) {
  __shared__ u16 wsh[64 * 128];         // 16 KB
  int tid = threadIdx.x;
  {
    const u32x4* g = (const u32x4*)WT;
    u32x4* l = (u32x4*)wsh;
#pragma unroll
    for (int i = 0; i < 4; i++)
      l[tid + i * 256] = g[tid + i * 256];
  }
  __syncthreads();

  int wave = tid >> 6;
  int lane = tid & 63;
  int quad = lane >> 4;
  int m16  = lane & 15;
  int r0 = blockIdx.x * 64 + wave * 16;

  int rowA = min(r0 + m16, NN - 1);
  const u16* px = xbin + (size_t)rowA * 128 + quad * 8;
  bf16x8 a[4];
#pragma unroll
  for (int j = 0; j < 4; j++) a[j] = *(const bf16x8*)(px + j * 32);

  f32x4 acc[4];
#pragma unroll
  for (int nt = 0; nt < 4; nt++) acc[nt] = (f32x4){0.f, 0.f, 0.f, 0.f};

  int swz = m16 & 7;
#pragma unroll
  for (int ks = 0; ks < 4; ks++) {
#pragma unroll
    for (int nt = 0; nt < 4; nt++) {
      const u16* bp = wsh + (nt * 16 + m16) * 128 + (((ks * 4 + quad) ^ swz) << 3);
      bf16x8 b = *(const bf16x8*)bp;
      acc[nt] = __builtin_amdgcn_mfma_f32_16x16x32_bf16(a[ks], b, acc[nt], 0, 0, 0);
    }
  }

  int rbase = r0 + quad * 4;
#pragma unroll
  for (int r = 0; r < 4; r++) {
    int row = rbase + r;
    if (row < NN) {
#pragma unroll
      for (int nt = 0; nt < 4; nt++)
        yb[(size_t)row * 64 + nt * 16 + m16] = f2bf(acc[nt][r]);
    }
  }
}

// ===== final layer: out = log_softmax(aggY + bl2 + xb2 @ Wr2) =====
__global__ __launch_bounds__(256)
void sage64f_k(const u16* __restrict__ aggy, const u16* __restrict__ xbin,
               const u16* __restrict__ WT, const float* __restrict__ bl,
               float* __restrict__ out) {
  __shared__ u16 wsh[64 * 128];         // 16 KB
  int tid = threadIdx.x;
  {
    const u32x4* g = (const u32x4*)WT;
    u32x4* l = (u32x4*)wsh;
#pragma unroll
    for (int i = 0; i < 4; i++)
      l[tid + i * 256] = g[tid + i * 256];
  }
  __syncthreads();

  int wave = tid >> 6;
  int lane = tid & 63;
  int quad = lane >> 4;
  int m16  = lane & 15;
  int r0 = blockIdx.x * 64 + wave * 16;

  int rowA = min(r0 + m16, NN - 1);
  const u16* px = xbin + (size_t)rowA * 128 + quad * 8;
  bf16x8 a[4];
#pragma unroll
  for (int j = 0; j < 4; j++) a[j] = *(const bf16x8*)(px + j * 32);

  f32x4 acc[4];
#pragma unroll
  for (int nt = 0; nt < 4; nt++) acc[nt] = (f32x4){0.f, 0.f, 0.f, 0.f};

  int swz = m16 & 7;
#pragma unroll
  for (int ks = 0; ks < 4; ks++) {
#pragma unroll
    for (int nt = 0; nt < 4; nt++) {
      const u16* bp = wsh + (nt * 16 + m16) * 128 + (((ks * 4 + quad) ^ swz) << 3);
      bf16x8 b = *(const bf16x8*)bp;
      acc[nt] = __builtin_amdgcn_mfma_f32_16x16x32_bf16(a[ks], b, acc[nt], 0, 0, 0);
    }
  }

  float bv[4];
#pragma unroll
  for (int nt = 0; nt < 4; nt++) bv[nt] = bl[nt * 16 + m16];

  int rbase = r0 + quad * 4;
#pragma unroll
  for (int r = 0; r < 4; r++) {
    int row = rbase + r;
    int rs = min(row, NN - 1);
    float v0 = acc[0][r] + bv[0] + bf2f(aggy[(size_t)rs * 64 + m16]);
    float v1 = acc[1][r] + bv[1] + bf2f(aggy[(size_t)rs * 64 + 16 + m16]);
    float v2 = acc[2][r] + bv[2] + bf2f(aggy[(size_t)rs * 64 + 32 + m16]);
    float v3 = acc[3][r] + bv[3] + bf2f(aggy[(size_t)rs * 64 + 48 + m16]);
    float m = fmaxf(fmaxf(v0, v1), fmaxf(v2, v3));
#pragma unroll
    for (int mk = 1; mk <= 8; mk <<= 1) m = fmaxf(m, __shfl_xor(m, mk));
    float s = __expf(v0 - m) + __expf(v1 - m) + __expf(v2 - m) + __expf(v3 - m);
#pragma unroll
    for (int mk = 1; mk <= 8; mk <<= 1) s += __shfl_xor(s, mk);
    float ls = m + __logf(s);
    if (row < NN) {
      float* orow = out + (size_t)row * 64;
      orow[m16]      = v0 - ls;
      orow[16 + m16] = v1 - ls;
      orow[32 + m16] = v2 - ls;
      orow[48 + m16] = v3 - ls;
    }
  }
}

// ======= graph pooling: 256 thr/block, odd/even node split + LDS combine =======
__global__ __launch_bounds__(256)
void pool_seg_k(const u16* __restrict__ xb, const int* __restrict__ cluster,
                float* __restrict__ g) {
  __shared__ float sh[256];
  int gid = blockIdx.x;          // 512
  int t = threadIdx.x;
  int ch = t & 127;
  int half = t >> 7;
  int lo = 0, hi = NN;
  while (lo < hi) { int mid = (lo + hi) >> 1; if (cluster[mid] < gid) lo = mid + 1; else hi = mid; }
  int beg = lo;
  hi = NN;
  while (lo < hi) { int mid = (lo + hi) >> 1; if (cluster[mid] < gid + 1) lo = mid + 1; else hi = mid; }
  int end = lo;
  float s0 = 0.f, s1 = 0.f;
  int n = beg + half;
  for (; n + 2 < end; n += 4) {
    s0 += bf2f(xb[(size_t)n * 128 + ch]);
    s1 += bf2f(xb[(size_t)(n + 2) * 128 + ch]);
  }
  if (n < end) s0 += bf2f(xb[(size_t)n * 128 + ch]);
  sh[t] = s0 + s1;
  __syncthreads();
  if (t < 128) {
    float s = sh[t] + sh[t + 128];
    g[gid * 128 + t] = s / fmaxf((float)(end - beg), 1.0f);
  }
}

extern "C" void kernel_launch(void* const* d_in, const int* in_sizes, int n_in,
                              void* d_out, int out_size, void* d_ws, size_t ws_size,
                              hipStream_t stream) {
  const float* x   = (const float*)d_in[0];
  const int*   ei  = (const int*)d_in[1];
  const int*   cl  = (const int*)d_in[2];
  const float* Wl0 = (const float*)d_in[3];
  const float* bl0 = (const float*)d_in[4];
  const float* Wr0 = (const float*)d_in[5];
  const float* Wl1 = (const float*)d_in[6];
  const float* bl1 = (const float*)d_in[7];
  const float* Wr1 = (const float*)d_in[8];
  const float* Wl2 = (const float*)d_in[9];
  const float* bl2 = (const float*)d_in[10];
  const float* Wr2 = (const float*)d_in[11];
  float* out = (float*)d_out;

  char* ws = (char*)d_ws;
  u16*   xb0     = (u16*)  (ws);                  // 12,800,000 B (bf16 of x)
  u16*   xb1     = (u16*)  (ws + 12800000);       // 12,800,000 B (relu layer0)
  u16*   xb2     = (u16*)  (ws + 25600000);       // 12,800,000 B (relu layer1)
  u16*   aggb    = (u16*)  (ws + 38400000);       // 12,800,000 B (layer0/1 agg; final: y2+aggy)
  u16*   y2      = aggb;                          //  6,400,000 B (xb2 @ Wl2, bf16)
  u16*   aggy    = (u16*)  (ws + 38400000 + 6400000); // 6,400,000 B
  u16*   WbT0    = (u16*)  (ws + 51200000);       //     65,536 B (pre-swizzled, K=256)
  u16*   WbT1    = (u16*)  (ws + 51265536);       //     65,536 B
  u16*   WlT2    = (u16*)  (ws + 51331072);       //     16,384 B (pre-swizzled, K=128)
  u16*   WrT2    = (u16*)  (ws + 51347456);       //     16,384 B
  int*   deg     = (int*)  (ws + 51363840);       //    200,000 B
  int*   row_ptr = (int*)  (ws + 51564032);       //    200,004 B (+pad)
  int*   cursor  = (int*)  (ws + 51764736);       //    200,000 B
  int*   perm    = (int*)  (ws + 51964736);       //  2,400,000 B
  int*   bsum    = (int*)  (ws + 54364736);       //        784 B
  int*   bofs    = (int*)  (ws + 54365568);       //        784 B
  // total ~54.4 MB

  float* out_lsm = out;            // [50000,64]
  float* out_pre = out + 3200000;  // [50000,128]
  float* out_g   = out + 9600000;  // [512,128]

  // ---- CSR build (once): deg -> 3-phase parallel scan -> fill ----
  hipMemsetAsync(deg, 0, 200000, stream);
  deg_count_k<<<2344, 256, 0, stream>>>(ei, deg);
  scan1_k<<<196, 256, 0, stream>>>(deg, bsum);
  scan2_k<<<1, 256, 0, stream>>>(bsum, bofs, row_ptr);
  scan3_k<<<196, 256, 0, stream>>>(deg, bofs, row_ptr, cursor);
  fill_k<<<2344, 256, 0, stream>>>(ei, cursor, perm);

  // ---- casts (x and weights) ----
  cast_k<<<12500, 256, 0, stream>>>(x, (u32*)xb0);
  castW_k<<<128, 256, 0, stream>>>(Wl0, Wr0, WbT0, 128);
  castW_k<<<128, 256, 0, stream>>>(Wl1, Wr1, WbT1, 128);
  castW64_k<<<32, 256, 0, stream>>>(Wl2, WlT2);
  castW64_k<<<32, 256, 0, stream>>>(Wr2, WrT2);

  // ---- layer 0 ----
  gather_w_k<128><<<12500, 256, 0, stream>>>(xb0, row_ptr, perm, aggb);
  sage_mfma_v2_k<false><<<782, 256, 0, stream>>>(aggb, xb0, WbT0, bl0, xb1, nullptr);

  // ---- layer 1 (pre-relu f32 straight to d_out) ----
  gather_w_k<128><<<12500, 256, 0, stream>>>(xb1, row_ptr, perm, aggb);
  sage_mfma_v2_k<true><<<782, 256, 0, stream>>>(aggb, xb1, WbT1, bl1, xb2, out_pre);

  // ---- graph pooling of relu(layer1) ----
  pool_seg_k<<<NG, 256, 0, stream>>>(xb2, cl, out_g);

  // ---- final layer via linearity: y2 = xb2@Wl2; aggY = gather-mean(y2);
  //      out = log_softmax(aggY + bl2 + xb2@Wr2) ----
  gemm64_k<<<782, 256, 0, stream>>>(xb2, WlT2, y2);
  gather_w_k<64><<<12500, 256, 0, stream>>>(y2, row_ptr, perm, aggy);
  sage64f_k<<<782, 256, 0, stream>>>(aggy, xb2, WrT2, bl2, out_lsm);
}

// Round 6
// 281.726 us; speedup vs baseline: 1.1209x; 1.0704x over previous
//
#include <hip/hip_runtime.h>
#include <math.h>

#define NN 50000
#define NE 600000
#define NG 512

typedef unsigned int u32;
typedef unsigned short u16;

typedef __attribute__((ext_vector_type(8))) short bf16x8;
typedef __attribute__((ext_vector_type(4))) float f32x4;
typedef __attribute__((ext_vector_type(4))) unsigned int u32x4;

__device__ __forceinline__ float bf2f(u16 u) {
  return __uint_as_float(((u32)u) << 16);
}
__device__ __forceinline__ u16 f2bf(float f) {
  u32 u = __float_as_uint(f);
  u32 lsb = (u >> 16) & 1u;
  u += 0x7fffu + lsb;          // RNE
  return (u16)(u >> 16);
}

// ================= fused prep: cast x, count degrees, cast+transpose weights ========
// blocks [0,12500): cast x->xb ; [12500,14844): deg_count ;
// [14844,14972): castW0 ; [14972,15100): castW1 ; [15100,15132): WlT2 ; [15132,15164): WrT2
__global__ __launch_bounds__(256)
void prep_k(const float* __restrict__ x, u32* __restrict__ xb,
            const int* __restrict__ ei, int* __restrict__ deg,
            const float* __restrict__ Wl0, const float* __restrict__ Wr0, u16* __restrict__ WbT0,
            const float* __restrict__ Wl1, const float* __restrict__ Wr1, u16* __restrict__ WbT1,
            const float* __restrict__ Wl2, u16* __restrict__ WlT2,
            const float* __restrict__ Wr2, u16* __restrict__ WrT2) {
  int b = blockIdx.x;
  int tid = threadIdx.x;
  if (b < 12500) {
    int t = b * 256 + tid;                       // 3,200,000 exactly
    float2 v = ((const float2*)x)[t];
    xb[t] = (u32)f2bf(v.x) | ((u32)f2bf(v.y) << 16);
  } else if (b < 14844) {
    int e = (b - 12500) * 256 + tid;
    if (e < NE) atomicAdd(&deg[ei[NE + e]], 1);
  } else if (b < 15100) {
    // K=256 weight cast+transpose, pre-swizzled: WbT[n][k], 16B chunk idx ^= (n&7)
    bool w1 = (b >= 14972);
    int t = (b - (w1 ? 14972 : 14844)) * 256 + tid;   // 128*256
    int n = t >> 8;
    int k = t & 255;
    const float* Wl = w1 ? Wl1 : Wl0;
    const float* Wr = w1 ? Wr1 : Wr0;
    float v = (k < 128) ? Wl[k * 128 + n] : Wr[(k - 128) * 128 + n];
    int c = k >> 3, e = k & 7;
    u16* dst = w1 ? WbT1 : WbT0;
    dst[n * 256 + (((c ^ (n & 7)) << 3) | e)] = f2bf(v);
  } else {
    // K=128 -> 64 cols, pre-swizzled
    bool wr = (b >= 15132);
    int t = (b - (wr ? 15132 : 15100)) * 256 + tid;   // 8192 = 64*128
    int n = t >> 7;
    int k = t & 127;
    const float* W = wr ? Wr2 : Wl2;
    float v = W[k * 64 + n];
    int c = k >> 3, e = k & 7;
    u16* dst = wr ? WrT2 : WlT2;
    dst[n * 128 + (((c ^ (n & 7)) << 3) | e)] = f2bf(v);
  }
}

// ================= CSR scans ========
__global__ __launch_bounds__(256)
void scan1_k(const int* __restrict__ deg, int* __restrict__ bsum) {
  __shared__ int s[256];
  int idx = blockIdx.x * 256 + threadIdx.x;
  int v = (idx < NN) ? deg[idx] : 0;
  s[threadIdx.x] = v;
  __syncthreads();
  for (int off = 128; off > 0; off >>= 1) {
    if (threadIdx.x < off) s[threadIdx.x] += s[threadIdx.x + off];
    __syncthreads();
  }
  if (threadIdx.x == 0) bsum[blockIdx.x] = s[0];
}

__global__ __launch_bounds__(256)
void scan2_k(const int* __restrict__ bsum, int* __restrict__ bofs, int* __restrict__ row_ptr) {
  __shared__ int s[256];
  int t = threadIdx.x;
  int v = (t < 196) ? bsum[t] : 0;
  s[t] = v;
  __syncthreads();
  for (int off = 1; off < 256; off <<= 1) {
    int add = (t >= off) ? s[t - off] : 0;
    __syncthreads();
    s[t] += add;
    __syncthreads();
  }
  if (t < 196) bofs[t] = s[t] - v;     // exclusive
  if (t == 0) row_ptr[NN] = NE;
}

__global__ __launch_bounds__(256)
void scan3_k(const int* __restrict__ deg, const int* __restrict__ bofs,
             int* __restrict__ row_ptr, int* __restrict__ cursor) {
  __shared__ int s[256];
  int idx = blockIdx.x * 256 + threadIdx.x;
  int t = threadIdx.x;
  int v = (idx < NN) ? deg[idx] : 0;
  s[t] = v;
  __syncthreads();
  for (int off = 1; off < 256; off <<= 1) {
    int add = (t >= off) ? s[t - off] : 0;
    __syncthreads();
    s[t] += add;
    __syncthreads();
  }
  if (idx < NN) {
    int p = bofs[blockIdx.x] + s[t] - v;
    row_ptr[idx] = p;
    cursor[idx] = p;
  }
}

__global__ __launch_bounds__(256)
void fill_k(const int* __restrict__ ei, int* __restrict__ cursor, int* __restrict__ perm) {
  int e = blockIdx.x * 256 + threadIdx.x;
  if (e >= NE) return;
  int pos = atomicAdd(&cursor[ei[NE + e]], 1);
  perm[pos] = ei[e];
}

// ===== gather-mean (128 ch): 4 nodes/wave, batch-8 dwordx4 (8 KB in flight) =====
// group = lane>>4 owns node; lane16 owns 16 B of the 256 B row.
__global__ __launch_bounds__(256)
void gather4_k(const u16* __restrict__ xb, const int* __restrict__ row_ptr,
               const int* __restrict__ perm, u16* __restrict__ aggb) {
  int wave = threadIdx.x >> 6;
  int lane = threadIdx.x & 63;
  int grp  = lane >> 4;
  int l16  = lane & 15;
  int n = (blockIdx.x * 4 + wave) * 4 + grp;     // 3125*4*4 = 50000
  int beg = row_ptr[n];
  int cnt = row_ptr[n + 1] - beg;
  int beg_s = min(beg, NE - 1);                  // safe base for clamped reads
  int last = max(cnt - 1, 0);
  int m = max(cnt, __shfl_xor(cnt, 16));
  int jmax = max(m, __shfl_xor(m, 32));          // wave-uniform loop bound
  float acc[8];
#pragma unroll
  for (int i = 0; i < 8; i++) acc[i] = 0.f;
  const u32x4* xv = (const u32x4*)xb;            // row = 16 chunks of 16 B
  for (int base = 0; base < jmax; base += 8) {
    int idx[8];
#pragma unroll
    for (int j = 0; j < 8; j++) idx[j] = perm[beg_s + min(base + j, last)];
    u32x4 v[8];
#pragma unroll
    for (int j = 0; j < 8; j++) v[j] = xv[(size_t)idx[j] * 16 + l16];
#pragma unroll
    for (int j = 0; j < 8; j++) {
      bool live = (base + j) < cnt;
#pragma unroll
      for (int w = 0; w < 4; w++) {
        u32 u = v[j][w];
        acc[2 * w]     += live ? __uint_as_float(u << 16) : 0.f;
        acc[2 * w + 1] += live ? __uint_as_float(u & 0xffff0000u) : 0.f;
      }
    }
  }
  float inv = 1.0f / fmaxf((float)cnt, 1.0f);
  u32x4 o;
#pragma unroll
  for (int w = 0; w < 4; w++)
    o[w] = (u32)f2bf(acc[2 * w] * inv) | ((u32)f2bf(acc[2 * w + 1] * inv) << 16);
  ((u32x4*)aggb)[(size_t)n * 16 + l16] = o;
}

// ===== gather-mean (64 ch rows = 128 B = ONE cache line/edge): 8 nodes/wave, batch-8 =====
// group = lane>>3 owns node; lane8 owns 16 B of the 128 B row.
__global__ __launch_bounds__(256)
void gather8_k(const u16* __restrict__ yb, const int* __restrict__ row_ptr,
               const int* __restrict__ perm, u16* __restrict__ aggy) {
  int wave = threadIdx.x >> 6;
  int lane = threadIdx.x & 63;
  int grp  = lane >> 3;               // 0..7
  int li   = lane & 7;
  int n = (blockIdx.x * 4 + wave) * 8 + grp;     // 1563*4*8 = 50016 (tail clamped)
  int ns = min(n, NN - 1);
  int beg = row_ptr[ns];
  int cnt = row_ptr[ns + 1] - beg;
  int beg_s = min(beg, NE - 1);
  int last = max(cnt - 1, 0);
  int m = max(cnt, __shfl_xor(cnt, 8));
  m = max(m, __shfl_xor(m, 16));
  int jmax = max(m, __shfl_xor(m, 32));          // wave-uniform loop bound
  float acc[8];
#pragma unroll
  for (int i = 0; i < 8; i++) acc[i] = 0.f;
  const u32x4* xv = (const u32x4*)yb;            // row = 8 chunks of 16 B
  for (int base = 0; base < jmax; base += 8) {
    int idx[8];
#pragma unroll
    for (int j = 0; j < 8; j++) idx[j] = perm[beg_s + min(base + j, last)];
    u32x4 v[8];
#pragma unroll
    for (int j = 0; j < 8; j++) v[j] = xv[(size_t)idx[j] * 8 + li];
#pragma unroll
    for (int j = 0; j < 8; j++) {
      bool live = (base + j) < cnt;
#pragma unroll
      for (int w = 0; w < 4; w++) {
        u32 u = v[j][w];
        acc[2 * w]     += live ? __uint_as_float(u << 16) : 0.f;
        acc[2 * w + 1] += live ? __uint_as_float(u & 0xffff0000u) : 0.f;
      }
    }
  }
  float inv = 1.0f / fmaxf((float)cnt, 1.0f);
  u32x4 o;
#pragma unroll
  for (int w = 0; w < 4; w++)
    o[w] = (u32)f2bf(acc[2 * w] * inv) | ((u32)f2bf(acc[2 * w + 1] * inv) << 16);
  if (n < NN) ((u32x4*)aggy)[(size_t)n * 8 + li] = o;
}

// ===== MFMA SAGE layer (Cout=128): block = 64 rows x 128 cols, W (K=256) in LDS =====
template<bool WRITE_PRE>
__global__ __launch_bounds__(256)
void sage_mfma_v2_k(const u16* __restrict__ aggb, const u16* __restrict__ xbin,
                    const u16* __restrict__ WbT, const float* __restrict__ bl,
                    u16* __restrict__ xb_out, float* __restrict__ out_pre) {
  __shared__ u16 wsh[128 * 256];        // 64 KB
  int tid = threadIdx.x;
  {
    const u32x4* g = (const u32x4*)WbT;
    u32x4* l = (u32x4*)wsh;
#pragma unroll
    for (int i = 0; i < 16; i++)
      l[tid + i * 256] = g[tid + i * 256];
  }
  __syncthreads();

  int wave = tid >> 6;
  int lane = tid & 63;
  int quad = lane >> 4;
  int m16  = lane & 15;
  int r0 = blockIdx.x * 64 + wave * 16;

  int rowA = min(r0 + m16, NN - 1);
  const u16* pa = aggb + (size_t)rowA * 128 + quad * 8;
  const u16* px = xbin + (size_t)rowA * 128 + quad * 8;
  bf16x8 a[8];
#pragma unroll
  for (int j = 0; j < 4; j++) a[j]     = *(const bf16x8*)(pa + j * 32);
#pragma unroll
  for (int j = 0; j < 4; j++) a[4 + j] = *(const bf16x8*)(px + j * 32);

  f32x4 acc[8];
#pragma unroll
  for (int nt = 0; nt < 8; nt++) acc[nt] = (f32x4){0.f, 0.f, 0.f, 0.f};

  int swz = m16 & 7;
#pragma unroll
  for (int ks = 0; ks < 8; ks++) {
#pragma unroll
    for (int nt = 0; nt < 8; nt++) {
      const u16* bp = wsh + (nt * 16 + m16) * 256 + (((quad + ks * 4) ^ swz) << 3);
      bf16x8 b = *(const bf16x8*)bp;
      acc[nt] = __builtin_amdgcn_mfma_f32_16x16x32_bf16(a[ks], b, acc[nt], 0, 0, 0);
    }
  }

  float bv[8];
#pragma unroll
  for (int nt = 0; nt < 8; nt++) bv[nt] = bl[nt * 16 + m16];

  int rbase = r0 + quad * 4;
#pragma unroll
  for (int r = 0; r < 4; r++) {
    int row = rbase + r;
    if (row < NN) {
#pragma unroll
      for (int nt = 0; nt < 8; nt++) {
        int col = nt * 16 + m16;
        float v = acc[nt][r] + bv[nt];
        if (WRITE_PRE) out_pre[(size_t)row * 128 + col] = v;
        xb_out[(size_t)row * 128 + col] = f2bf(fmaxf(v, 0.f));
      }
    }
  }
}

// ===== pre-GEMM for final layer: y2 = xb2 @ Wl2 (K=128 -> 64 cols, bf16 out) =====
__global__ __launch_bounds__(256)
void gemm64_k(const u16* __restrict__ xbin, const u16* __restrict__ WT,
              u16* __restrict__ yb) {
  __shared__ u16 wsh[64 * 128];         // 16 KB
  int tid = threadIdx.x;
  {
    const u32x4* g = (const u32x4*)WT;
    u32x4* l = (u32x4*)wsh;
#pragma unroll
    for (int i = 0; i < 4; i++)
      l[tid + i * 256] = g[tid + i * 256];
  }
  __syncthreads();

  int wave = tid >> 6;
  int lane = tid & 63;
  int quad = lane >> 4;
  int m16  = lane & 15;
  int r0 = blockIdx.x * 64 + wave * 16;

  int rowA = min(r0 + m16, NN - 1);
  const u16* px = xbin + (size_t)rowA * 128 + quad * 8;
  bf16x8 a[4];
#pragma unroll
  for (int j = 0; j < 4; j++) a[j] = *(const bf16x8*)(px + j * 32);

  f32x4 acc[4];
#pragma unroll
  for (int nt = 0; nt < 4; nt++) acc[nt] = (f32x4){0.f, 0.f, 0.f, 0.f};

  int swz = m16 & 7;
#pragma unroll
  for (int ks = 0; ks < 4; ks++) {
#pragma unroll
    for (int nt = 0; nt < 4; nt++) {
      const u16* bp = wsh + (nt * 16 + m16) * 128 + (((ks * 4 + quad) ^ swz) << 3);
      bf16x8 b = *(const bf16x8*)bp;
      acc[nt] = __builtin_amdgcn_mfma_f32_16x16x32_bf16(a[ks], b, acc[nt], 0, 0, 0);
    }
  }

  int rbase = r0 + quad * 4;
#pragma unroll
  for (int r = 0; r < 4; r++) {
    int row = rbase + r;
    if (row < NN) {
#pragma unroll
      for (int nt = 0; nt < 4; nt++)
        yb[(size_t)row * 64 + nt * 16 + m16] = f2bf(acc[nt][r]);
    }
  }
}

// ===== final layer: out = log_softmax(aggY + bl2 + xb2 @ Wr2) =====
__global__ __launch_bounds__(256)
void sage64f_k(const u16* __restrict__ aggy, const u16* __restrict__ xbin,
               const u16* __restrict__ WT, const float* __restrict__ bl,
               float* __restrict__ out) {
  __shared__ u16 wsh[64 * 128];         // 16 KB
  int tid = threadIdx.x;
  {
    const u32x4* g = (const u32x4*)WT;
    u32x4* l = (u32x4*)wsh;
#pragma unroll
    for (int i = 0; i < 4; i++)
      l[tid + i * 256] = g[tid + i * 256];
  }
  __syncthreads();

  int wave = tid >> 6;
  int lane = tid & 63;
  int quad = lane >> 4;
  int m16  = lane & 15;
  int r0 = blockIdx.x * 64 + wave * 16;

  int rowA = min(r0 + m16, NN - 1);
  const u16* px = xbin + (size_t)rowA * 128 + quad * 8;
  bf16x8 a[4];
#pragma unroll
  for (int j = 0; j < 4; j++) a[j] = *(const bf16x8*)(px + j * 32);

  f32x4 acc[4];
#pragma unroll
  for (int nt = 0; nt < 4; nt++) acc[nt] = (f32x4){0.f, 0.f, 0.f, 0.f};

  int swz = m16 & 7;
#pragma unroll
  for (int ks = 0; ks < 4; ks++) {
#pragma unroll
    for (int nt = 0; nt < 4; nt++) {
      const u16* bp = wsh + (nt * 16 + m16) * 128 + (((ks * 4 + quad) ^ swz) << 3);
      bf16x8 b = *(const bf16x8*)bp;
      acc[nt] = __builtin_amdgcn_mfma_f32_16x16x32_bf16(a[ks], b, acc[nt], 0, 0, 0);
    }
  }

  float bv[4];
#pragma unroll
  for (int nt = 0; nt < 4; nt++) bv[nt] = bl[nt * 16 + m16];

  int rbase = r0 + quad * 4;
#pragma unroll
  for (int r = 0; r < 4; r++) {
    int row = rbase + r;
    int rs = min(row, NN - 1);
    float v0 = acc[0][r] + bv[0] + bf2f(aggy[(size_t)rs * 64 + m16]);
    float v1 = acc[1][r] + bv[1] + bf2f(aggy[(size_t)rs * 64 + 16 + m16]);
    float v2 = acc[2][r] + bv[2] + bf2f(aggy[(size_t)rs * 64 + 32 + m16]);
    float v3 = acc[3][r] + bv[3] + bf2f(aggy[(size_t)rs * 64 + 48 + m16]);
    float m = fmaxf(fmaxf(v0, v1), fmaxf(v2, v3));
#pragma unroll
    for (int mk = 1; mk <= 8; mk <<= 1) m = fmaxf(m, __shfl_xor(m, mk));
    float s = __expf(v0 - m) + __expf(v1 - m) + __expf(v2 - m) + __expf(v3 - m);
#pragma unroll
    for (int mk = 1; mk <= 8; mk <<= 1) s += __shfl_xor(s, mk);
    float ls = m + __logf(s);
    if (row < NN) {
      float* orow = out + (size_t)row * 64;
      orow[m16]      = v0 - ls;
      orow[16 + m16] = v1 - ls;
      orow[32 + m16] = v2 - ls;
      orow[48 + m16] = v3 - ls;
    }
  }
}

// ======= graph pooling: 256 thr/block, odd/even node split + LDS combine =======
__global__ __launch_bounds__(256)
void pool_seg_k(const u16* __restrict__ xb, const int* __restrict__ cluster,
                float* __restrict__ g) {
  __shared__ float sh[256];
  int gid = blockIdx.x;          // 512
  int t = threadIdx.x;
  int ch = t & 127;
  int half = t >> 7;
  int lo = 0, hi = NN;
  while (lo < hi) { int mid = (lo + hi) >> 1; if (cluster[mid] < gid) lo = mid + 1; else hi = mid; }
  int beg = lo;
  hi = NN;
  while (lo < hi) { int mid = (lo + hi) >> 1; if (cluster[mid] < gid + 1) lo = mid + 1; else hi = mid; }
  int end = lo;
  float s0 = 0.f, s1 = 0.f;
  int n = beg + half;
  for (; n + 2 < end; n += 4) {
    s0 += bf2f(xb[(size_t)n * 128 + ch]);
    s1 += bf2f(xb[(size_t)(n + 2) * 128 + ch]);
  }
  if (n < end) s0 += bf2f(xb[(size_t)n * 128 + ch]);
  sh[t] = s0 + s1;
  __syncthreads();
  if (t < 128) {
    float s = sh[t] + sh[t + 128];
    g[gid * 128 + t] = s / fmaxf((float)(end - beg), 1.0f);
  }
}

extern "C" void kernel_launch(void* const* d_in, const int* in_sizes, int n_in,
                              void* d_out, int out_size, void* d_ws, size_t ws_size,
                              hipStream_t stream) {
  const float* x   = (const float*)d_in[0];
  const int*   ei  = (const int*)d_in[1];
  const int*   cl  = (const int*)d_in[2];
  const float* Wl0 = (const float*)d_in[3];
  const float* bl0 = (const float*)d_in[4];
  const float* Wr0 = (const float*)d_in[5];
  const float* Wl1 = (const float*)d_in[6];
  const float* bl1 = (const float*)d_in[7];
  const float* Wr1 = (const float*)d_in[8];
  const float* Wl2 = (const float*)d_in[9];
  const float* bl2 = (const float*)d_in[10];
  const float* Wr2 = (const float*)d_in[11];
  float* out = (float*)d_out;

  char* ws = (char*)d_ws;
  u16*   xb0     = (u16*)  (ws);                  // 12,800,000 B (bf16 of x)
  u16*   xb1     = (u16*)  (ws + 12800000);       // 12,800,000 B (relu layer0)
  u16*   xb2     = (u16*)  (ws + 25600000);       // 12,800,000 B (relu layer1)
  u16*   aggb    = (u16*)  (ws + 38400000);       // 12,800,000 B (layer0/1 agg; final: y2+aggy)
  u16*   y2      = aggb;                          //  6,400,000 B (xb2 @ Wl2, bf16)
  u16*   aggy    = (u16*)  (ws + 38400000 + 6400000); // 6,400,000 B
  u16*   WbT0    = (u16*)  (ws + 51200000);       //     65,536 B (pre-swizzled, K=256)
  u16*   WbT1    = (u16*)  (ws + 51265536);       //     65,536 B
  u16*   WlT2    = (u16*)  (ws + 51331072);       //     16,384 B (pre-swizzled, K=128)
  u16*   WrT2    = (u16*)  (ws + 51347456);       //     16,384 B
  int*   deg     = (int*)  (ws + 51363840);       //    200,000 B
  int*   row_ptr = (int*)  (ws + 51564032);       //    200,004 B (+pad)
  int*   cursor  = (int*)  (ws + 51764736);       //    200,000 B
  int*   perm    = (int*)  (ws + 51964736);       //  2,400,000 B
  int*   bsum    = (int*)  (ws + 54364736);       //        784 B
  int*   bofs    = (int*)  (ws + 54365568);       //        784 B
  // total ~54.4 MB

  float* out_lsm = out;            // [50000,64]
  float* out_pre = out + 3200000;  // [50000,128]
  float* out_g   = out + 9600000;  // [512,128]

  // ---- fused prep (cast x, deg count, all weight casts) ----
  hipMemsetAsync(deg, 0, 200000, stream);
  prep_k<<<15164, 256, 0, stream>>>(x, (u32*)xb0, ei, deg,
                                    Wl0, Wr0, WbT0, Wl1, Wr1, WbT1,
                                    Wl2, WlT2, Wr2, WrT2);

  // ---- CSR scans + fill ----
  scan1_k<<<196, 256, 0, stream>>>(deg, bsum);
  scan2_k<<<1, 256, 0, stream>>>(bsum, bofs, row_ptr);
  scan3_k<<<196, 256, 0, stream>>>(deg, bofs, row_ptr, cursor);
  fill_k<<<2344, 256, 0, stream>>>(ei, cursor, perm);

  // ---- layer 0 ----
  gather4_k<<<3125, 256, 0, stream>>>(xb0, row_ptr, perm, aggb);
  sage_mfma_v2_k<false><<<782, 256, 0, stream>>>(aggb, xb0, WbT0, bl0, xb1, nullptr);

  // ---- layer 1 (pre-relu f32 straight to d_out) ----
  gather4_k<<<3125, 256, 0, stream>>>(xb1, row_ptr, perm, aggb);
  sage_mfma_v2_k<true><<<782, 256, 0, stream>>>(aggb, xb1, WbT1, bl1, xb2, out_pre);

  // ---- graph pooling of relu(layer1) ----
  pool_seg_k<<<NG, 256, 0, stream>>>(xb2, cl, out_g);

  // ---- final layer via linearity: y2 = xb2@Wl2; aggY = gather-mean(y2);
  //      out = log_softmax(aggY + bl2 + xb2@Wr2) ----
  gemm64_k<<<782, 256, 0, stream>>>(xb2, WlT2, y2);
  gather8_k<<<1563, 256, 0, stream>>>(y2, row_ptr, perm, aggy);
  sage64f_k<<<782, 256, 0, stream>>>(aggy, xb2, WrT2, bl2, out_lsm);
}